// Round 6
// baseline (2483.254 us; speedup 1.0000x reference)
//
#include <hip/hip_runtime.h>
#include <math.h>
#include <stdint.h>

// ---------------------------------------------------------------------------
// SNN forward — R13: 4-row spike-UNION gather (waves split by h-quadrant)
// to cut L2 bytes ~2x + R10 WtO-in-LDS sum_o + R12 GEMM.
//
// Bit-exactness contract (R3..R12, absmax 4.882812e-4):
//   - layer-1: c=0; for d ascending: c=fmaf(w,x,c); then __fadd_rn(c,bias)
//   - spike layers: per (row,h) sum over spiking k ASCENDING, sequential
//     __fadd_rn chain seeded 0. R13 walks the UNION list (ascending) and
//     adds (rowbit ? w : 0.0f); +0.0 adds are exact identities (partial
//     sums never -0), so each chain is bit-identical. Sentinel k=256 hits
//     the zeroed row with rm=0.
//   - LIF: individually-rounded fp32 ops, reset from PREVIOUS mem
//
// R12 post-mortem: depth-4 + pipelined sum_o regressed (817->933us, VALU
// work up, no latency won). Cumulative evidence: R10's 817us == L2 BW
// ceiling (4 rows x 2 layers x p*256KB ~ 720-920KB/step/CU ~ 29-37TB/s
// aggregate). Only BYTES move the needle now. Union gather: block reads
// each spiking weight row ONCE (4 waves x 256B), membership nibble steers
// per-row accumulation. Bytes x(1-(1-p)^4)/(4p) ~ 0.5.
// Masks exchanged via LDS, parity double-buffered, 3 barriers/step.
// ---------------------------------------------------------------------------

namespace {

constexpr int Bsz = 1024;
constexpr int Dd  = 256;
constexpr int Tt  = 128;
constexpr int Hh  = 256;
constexpr int Oo  = 64;

// Wt[c*R + r] = W[r*C + c] for c<C; row c==C zeroed (sparse sentinel target).
__global__ void pack_t(const float* __restrict__ W, float* __restrict__ Wt,
                       int R, int C) {
    int idx = blockIdx.x * 256 + threadIdx.x;
    if (idx >= (C + 1) * R) return;
    int c = idx / R, r = idx - c * R;
    Wt[idx] = (c < C) ? W[(size_t)r * C + c] : 0.f;
}

// WtO[k*128 + o]: o<64 -> W_f[o][k], o>=64 -> W_a[o-64][k]; row k==256 zeroed.
__global__ void pack_o(const float* __restrict__ Wf, const float* __restrict__ Wa,
                       float* __restrict__ WtO) {
    int idx = blockIdx.x * 256 + threadIdx.x;
    if (idx >= 257 * 128) return;
    int k = idx >> 7, o = idx & 127;
    float v = 0.f;
    if (k < 256) v = (o < 64) ? Wf[(size_t)o * 256 + k] : Wa[(size_t)(o - 64) * 256 + k];
    WtO[idx] = v;
}

__device__ __forceinline__ float clamp01(float v) { return fminf(fmaxf(v, 0.f), 1.f); }

__device__ __forceinline__ bool lif_step(float& m, float cur, float B, float Th) {
    const float r = (__fsub_rn(m, Th) > 0.f) ? Th : 0.f;   // reset from PREVIOUS mem
    m = __fsub_rn(__fadd_rn(__fmul_rn(B, m), cur), r);
    return __fsub_rn(m, Th) > 0.f;
}

// ---- union compaction -----------------------------------------------------
// mb[r][q]: 64-bit spike word of row r, h-word q (q = producing wave).
// Emits ascending-neuron u16 entries: (n | rowmask<<12). Lane owns union
// neurons 4L..4L+3. Pads to x8 with sentinel Hh (rm=0). Returns npad.
__device__ __forceinline__ int compact_u(int lane, const uint64_t (*mb)[4],
                                         uint16_t* lst) {
    const uint64_t m00 = mb[0][0], m10 = mb[1][0], m20 = mb[2][0], m30 = mb[3][0];
    const uint64_t m01 = mb[0][1], m11 = mb[1][1], m21 = mb[2][1], m31 = mb[3][1];
    const uint64_t m02 = mb[0][2], m12 = mb[1][2], m22 = mb[2][2], m32 = mb[3][2];
    const uint64_t m03 = mb[0][3], m13 = mb[1][3], m23 = mb[2][3], m33 = mb[3][3];
    const uint64_t U0 = m00 | m10 | m20 | m30;
    const uint64_t U1 = m01 | m11 | m21 | m31;
    const uint64_t U2 = m02 | m12 | m22 | m32;
    const uint64_t U3 = m03 | m13 | m23 | m33;
    const int p0 = (int)__popcll(U0);
    const int p1 = (int)__popcll(U1);
    const int p2 = (int)__popcll(U2);
    const int p3 = (int)__popcll(U3);
    const int q  = lane >> 4;
    const uint64_t Uq = (q & 2) ? ((q & 1) ? U3 : U2) : ((q & 1) ? U1 : U0);
    const uint64_t r0q = (q & 2) ? ((q & 1) ? m03 : m02) : ((q & 1) ? m01 : m00);
    const uint64_t r1q = (q & 2) ? ((q & 1) ? m13 : m12) : ((q & 1) ? m11 : m10);
    const uint64_t r2q = (q & 2) ? ((q & 1) ? m23 : m22) : ((q & 1) ? m21 : m20);
    const uint64_t r3q = (q & 2) ? ((q & 1) ? m33 : m32) : ((q & 1) ? m31 : m30);
    const int posb = (lane & 15) << 2;
    const int nib  = (int)((Uq >> posb) & 0xFull);
    const int base = ((q >= 1) ? p0 : 0) + ((q >= 2) ? p1 : 0) + ((q >= 3) ? p2 : 0);
    const int r0   = base + (int)__popcll(Uq & ((1ull << posb) - 1ull));
    const int s1 = nib & 1;
    const int s2 = s1 + ((nib >> 1) & 1);
    const int s3 = s2 + ((nib >> 2) & 1);
    const int nb = lane << 2;
    #define RM_AT(pos) ( (int)((r0q >> (pos)) & 1)        | ((int)((r1q >> (pos)) & 1) << 1) \
                       | ((int)((r2q >> (pos)) & 1) << 2) | ((int)((r3q >> (pos)) & 1) << 3) )
    if (nib & 1) lst[r0]      = (uint16_t)( nb      | (RM_AT(posb    ) << 12));
    if (nib & 2) lst[r0 + s1] = (uint16_t)((nb + 1) | (RM_AT(posb + 1) << 12));
    if (nib & 4) lst[r0 + s2] = (uint16_t)((nb + 2) | (RM_AT(posb + 2) << 12));
    if (nib & 8) lst[r0 + s3] = (uint16_t)((nb + 3) | (RM_AT(posb + 3) << 12));
    #undef RM_AT
    const int n    = p0 + p1 + p2 + p3;
    const int npad = (n + 7) & ~7;
    if (lane < npad - n) lst[n + lane] = (uint16_t)Hh;   // sentinel, rm=0
    return npad;
}

// ---- per-row compaction (for sum_o), nib derived from M --------------------
__device__ __forceinline__ int compact_row(int lane, const uint64_t* M,
                                           uint16_t* lst) {
    const int nib = (int)((M[lane >> 4] >> ((lane & 15) << 2)) & 0xFull);
    const int p0 = (int)__popcll(M[0]);
    const int p1 = (int)__popcll(M[1]);
    const int p2 = (int)__popcll(M[2]);
    const int p3 = (int)__popcll(M[3]);
    const int q  = lane >> 4;
    const int base = ((q >= 1) ? p0 : 0) + ((q >= 2) ? p1 : 0) + ((q >= 3) ? p2 : 0);
    const uint64_t mq = (q & 2) ? ((q & 1) ? M[3] : M[2])
                                : ((q & 1) ? M[1] : M[0]);
    const int posb = (lane & 15) << 2;
    const int r0 = base + (int)__popcll(mq & ((1ull << posb) - 1ull));
    const int s1 = nib & 1;
    const int s2 = s1 + ((nib >> 1) & 1);
    const int s3 = s2 + ((nib >> 2) & 1);
    const int nb = lane << 2;
    if (nib & 1) lst[r0]      = (uint16_t)nb;
    if (nib & 2) lst[r0 + s1] = (uint16_t)(nb + 1);
    if (nib & 4) lst[r0 + s2] = (uint16_t)(nb + 2);
    if (nib & 8) lst[r0 + s3] = (uint16_t)(nb + 3);
    const int n    = p0 + p1 + p2 + p3;
    const int npad = (n + 7) & ~7;
    if (lane < npad - n) lst[n + lane] = (uint16_t)Hh;
    return npad;
}

// ---- union gather: 8 dword loads per group, depth-3 pinned rotation -------
// Lane loads the single float of its h (offW bytes into each 1KB row).

__device__ __forceinline__ void issue8u(const char* __restrict__ tab,
                                        uint4 I, int offW, float* w) {
    const int k[8] = {(int)(I.x & 0xFFFu), (int)((I.x >> 16) & 0xFFFu),
                      (int)(I.y & 0xFFFu), (int)((I.y >> 16) & 0xFFFu),
                      (int)(I.z & 0xFFFu), (int)((I.z >> 16) & 0xFFFu),
                      (int)(I.w & 0xFFFu), (int)((I.w >> 16) & 0xFFFu)};
    #pragma unroll
    for (int i = 0; i < 8; ++i)
        w[i] = *(const float*)(tab + (k[i] << 10) + offW);
}

__device__ __forceinline__ void cons8u(float* acc, const float* w, uint4 I) {
    const int rm[8] = {(int)((I.x >> 12) & 0xFu), (int)((I.x >> 28) & 0xFu),
                       (int)((I.y >> 12) & 0xFu), (int)((I.y >> 28) & 0xFu),
                       (int)((I.z >> 12) & 0xFu), (int)((I.z >> 28) & 0xFu),
                       (int)((I.w >> 12) & 0xFu), (int)((I.w >> 28) & 0xFu)};
    #pragma unroll
    for (int i = 0; i < 8; ++i) {
        acc[0] = __fadd_rn(acc[0], (rm[i] & 1) ? w[i] : 0.0f);
        acc[1] = __fadd_rn(acc[1], (rm[i] & 2) ? w[i] : 0.0f);
        acc[2] = __fadd_rn(acc[2], (rm[i] & 4) ? w[i] : 0.0f);
        acc[3] = __fadd_rn(acc[3], (rm[i] & 8) ? w[i] : 0.0f);
    }
}

__device__ __forceinline__ void sum_hu(const uint16_t* lst, int nbat,
                                       const float* __restrict__ tab, int offW,
                                       float* acc) {
    acc[0] = 0.f; acc[1] = 0.f; acc[2] = 0.f; acc[3] = 0.f;
    if (nbat == 0) return;
    const char* tb = (const char*)tab;
    uint4 IA, IB, IC;
    float WA[8], WB[8], WC[8];
    IA = *(const uint4*)(lst);      issue8u(tb, IA, offW, WA);
    if (nbat == 1) { cons8u(acc, WA, IA); return; }
    IB = *(const uint4*)(lst + 8);  issue8u(tb, IB, offW, WB);
    if (nbat == 2) { cons8u(acc, WA, IA); cons8u(acc, WB, IB); return; }
    IC = *(const uint4*)(lst + 16); issue8u(tb, IC, offW, WC);
    __builtin_amdgcn_sched_barrier(0);
    int i = 3;
    for (; i + 2 < nbat; i += 3) {
        cons8u(acc, WA, IA);
        IA = *(const uint4*)(lst + 8 * i);       issue8u(tb, IA, offW, WA);
        __builtin_amdgcn_sched_barrier(0);
        cons8u(acc, WB, IB);
        IB = *(const uint4*)(lst + 8 * (i + 1)); issue8u(tb, IB, offW, WB);
        __builtin_amdgcn_sched_barrier(0);
        cons8u(acc, WC, IC);
        IC = *(const uint4*)(lst + 8 * (i + 2)); issue8u(tb, IC, offW, WC);
        __builtin_amdgcn_sched_barrier(0);
    }
    const int r = nbat - i;
    if (r == 0) {
        cons8u(acc, WA, IA); cons8u(acc, WB, IB); cons8u(acc, WC, IC);
    } else if (r == 1) {
        cons8u(acc, WA, IA);
        IA = *(const uint4*)(lst + 8 * i); issue8u(tb, IA, offW, WA);
        cons8u(acc, WB, IB); cons8u(acc, WC, IC); cons8u(acc, WA, IA);
    } else {
        cons8u(acc, WA, IA);
        IA = *(const uint4*)(lst + 8 * i);       issue8u(tb, IA, offW, WA);
        cons8u(acc, WB, IB);
        IB = *(const uint4*)(lst + 8 * (i + 1)); issue8u(tb, IB, offW, WB);
        cons8u(acc, WC, IC); cons8u(acc, WA, IA); cons8u(acc, WB, IB);
    }
}

// ---- output-layer gather from LDS-resident WtO (R10 serial form) ----------

__device__ __forceinline__ float2 sum_o_lds(const uint16_t* lst, int nbat,
                                            const float* tab, int offB) {
    float2 c = {0.f, 0.f};
    const char* tb = (const char*)tab;
    for (int i = 0; i < nbat; ++i) {
        const uint4 I = *(const uint4*)(lst + 8 * i);
        float2 w[8];
        w[0] = *(const float2*)(tb + ((I.x & 0xffffu) << 9) + offB);
        w[1] = *(const float2*)(tb + ((I.x >> 16)    << 9) + offB);
        w[2] = *(const float2*)(tb + ((I.y & 0xffffu) << 9) + offB);
        w[3] = *(const float2*)(tb + ((I.y >> 16)    << 9) + offB);
        w[4] = *(const float2*)(tb + ((I.z & 0xffffu) << 9) + offB);
        w[5] = *(const float2*)(tb + ((I.z >> 16)    << 9) + offB);
        w[6] = *(const float2*)(tb + ((I.w & 0xffffu) << 9) + offB);
        w[7] = *(const float2*)(tb + ((I.w >> 16)    << 9) + offB);
        #pragma unroll
        for (int j = 0; j < 8; ++j) {
            c.x = __fadd_rn(c.x, w[j].x);
            c.y = __fadd_rn(c.y, w[j].y);
        }
    }
    return c;
}

// ------------- recurrent kernel: 4 waves, h-split union gather -------------
// Block = 4 batch rows b0..b0+3. Wave wq owns h-quadrant [wq*64, wq*64+64)
// for ALL 4 rows (hidden layers) and row b0+wq for sum_o/output.
// Per lane: h = wq*64 + lane... wait lane in [0,64) -> h = wq*64 + lane.
// Spike masks exchanged via LDS mbuf[parity][layer][row][hword].
__global__ __launch_bounds__(256, 1) void snn_rec(
    const float* __restrict__ cur1,     // [b][t_local][h]
    const float* __restrict__ Wt_h, const float* __restrict__ Wt_h1,
    const float* __restrict__ WtO,
    const float* __restrict__ beta1, const float* __restrict__ thr1,
    const float* __restrict__ b_h,  const float* __restrict__ beta2, const float* __restrict__ thr2,
    const float* __restrict__ b_h1,
    const float* __restrict__ b_f,  const float* __restrict__ beta_f,
    const float* __restrict__ b_a,  const float* __restrict__ beta_a,
    float* __restrict__ m1s, float* __restrict__ m2s, float* __restrict__ m3s,
    float* __restrict__ mos, float* __restrict__ out,
    int TC, int first)
{
    __shared__ __attribute__((aligned(16))) float ldsO[257 * 128];   // 128.5 KB
    __shared__ __attribute__((aligned(16))) uint16_t lists[4][272];
    __shared__ __attribute__((aligned(16))) uint64_t mbuf[2][3][4][4];

    const int tid  = threadIdx.x;
    const int lane = tid & 63;
    const int wq   = tid >> 6;            // wave id = h-quadrant
    const int b0   = blockIdx.x * 4;
    const int brow = b0 + wq;             // this wave's row for sum_o/output
    uint16_t* lst  = lists[wq];
    const int hq   = wq * 64 + lane;      // this lane's hidden neuron
    const int offW = hq * 4;              // byte offset into 1KB hidden rows
    const int off2 = lane * 2;            // output slot base 2L (row brow)
    const int offBo = lane * 8;           // byte offset into 512B output rows

    // ---- stage WtO into LDS (one-time; bit-identical values) --------------
    {
        const float4* s4 = (const float4*)WtO;
        float4* d4 = (float4*)ldsO;
        for (int v = tid; v < (257 * 128) / 4; v += 256) d4[v] = s4[v];
    }
    __syncthreads();

    // per-lane layer params at h = hq
    const float B1s  = clamp01(beta1[hq]);
    const float Th1s = thr1[hq];
    const float bhs  = b_h[hq];
    const float B2s  = clamp01(beta2[hq]);
    const float Th2s = thr2[hq];
    const float bh1s = b_h1[hq];

    // output params for row brow (same mapping as R10)
    const int oo = off2 & 63;
    const float* bop = (lane < 32) ? b_f    : b_a;
    const float* Bop = (lane < 32) ? beta_f : beta_a;
    const float bo0 = bop[oo], bo1 = bop[oo + 1];
    const float Bo0 = clamp01(Bop[oo]), Bo1 = clamp01(Bop[oo + 1]);

    float m1a[4], m2a[4], m3a[4];
    float mo0, mo1;
    if (first) {
        #pragma unroll
        for (int r = 0; r < 4; ++r) { m1a[r] = 0.f; m2a[r] = 0.f; m3a[r] = 0.f; }
        mo0 = mo1 = 0.f;
    } else {
        #pragma unroll
        for (int r = 0; r < 4; ++r) {
            m1a[r] = m1s[(size_t)(b0 + r) * Hh + hq];
            m2a[r] = m2s[(size_t)(b0 + r) * Hh + hq];
            m3a[r] = m3s[(size_t)(b0 + r) * Hh + hq];
        }
        const float2 mo = *(const float2*)(mos + (size_t)brow * 128 + off2);
        mo0 = mo.x; mo1 = mo.y;
    }

    // cur1 pointers: lane reads cur1[(b0+r)*TC + t][hq]
    const float* __restrict__ curb0 = cur1 + ((size_t)(b0 + 0) * TC) * Hh + hq;
    const float* __restrict__ curb1 = cur1 + ((size_t)(b0 + 1) * TC) * Hh + hq;
    const float* __restrict__ curb2 = cur1 + ((size_t)(b0 + 2) * TC) * Hh + hq;
    const float* __restrict__ curb3 = cur1 + ((size_t)(b0 + 3) * TC) * Hh + hq;
    float cur0 = curb0[0], cur1v = curb1[0], cur2v = curb2[0], cur3v = curb3[0];

    float acc[4];

    for (int t = 0; t < TC; ++t) {
        const int par = t & 1;
        // ---- layer 1 LIF (per lane: 1 h x 4 rows) -------------------------
        const uint64_t W0 = __ballot(lif_step(m1a[0], cur0,  B1s, Th1s));
        const uint64_t W1 = __ballot(lif_step(m1a[1], cur1v, B1s, Th1s));
        const uint64_t W2 = __ballot(lif_step(m1a[2], cur2v, B1s, Th1s));
        const uint64_t W3 = __ballot(lif_step(m1a[3], cur3v, B1s, Th1s));
        if (lane == 0) {
            mbuf[par][0][0][wq] = W0; mbuf[par][0][1][wq] = W1;
            mbuf[par][0][2][wq] = W2; mbuf[par][0][3][wq] = W3;
        }
        if (t + 1 < TC) {   // prefetch next cur while masks exchange
            cur0  = curb0[(size_t)(t + 1) * Hh];
            cur1v = curb1[(size_t)(t + 1) * Hh];
            cur2v = curb2[(size_t)(t + 1) * Hh];
            cur3v = curb3[(size_t)(t + 1) * Hh];
        }
        __syncthreads();                                       // barrier A

        // ---- layer 2: union gather over Wt_h ------------------------------
        int npad = compact_u(lane, mbuf[par][0], lst);
        sum_hu(lst, npad >> 3, Wt_h, offW, acc);
        const uint64_t V0 = __ballot(lif_step(m2a[0], __fadd_rn(acc[0], bhs), B2s, Th2s));
        const uint64_t V1 = __ballot(lif_step(m2a[1], __fadd_rn(acc[1], bhs), B2s, Th2s));
        const uint64_t V2 = __ballot(lif_step(m2a[2], __fadd_rn(acc[2], bhs), B2s, Th2s));
        const uint64_t V3 = __ballot(lif_step(m2a[3], __fadd_rn(acc[3], bhs), B2s, Th2s));
        if (lane == 0) {
            mbuf[par][1][0][wq] = V0; mbuf[par][1][1][wq] = V1;
            mbuf[par][1][2][wq] = V2; mbuf[par][1][3][wq] = V3;
        }
        __syncthreads();                                       // barrier B

        // ---- layer 3: union gather over Wt_h1 (beta2/thr2 reused — bug) ---
        npad = compact_u(lane, mbuf[par][1], lst);
        sum_hu(lst, npad >> 3, Wt_h1, offW, acc);
        const uint64_t X0 = __ballot(lif_step(m3a[0], __fadd_rn(acc[0], bh1s), B2s, Th2s));
        const uint64_t X1 = __ballot(lif_step(m3a[1], __fadd_rn(acc[1], bh1s), B2s, Th2s));
        const uint64_t X2 = __ballot(lif_step(m3a[2], __fadd_rn(acc[2], bh1s), B2s, Th2s));
        const uint64_t X3 = __ballot(lif_step(m3a[3], __fadd_rn(acc[3], bh1s), B2s, Th2s));
        if (lane == 0) {
            mbuf[par][2][0][wq] = X0; mbuf[par][2][1][wq] = X1;
            mbuf[par][2][2][wq] = X2; mbuf[par][2][3][wq] = X3;
        }
        __syncthreads();                                       // barrier C

        // ---- output LI neurons: row brow, gather from LDS-resident WtO ----
        uint64_t M3r[4];
        #pragma unroll
        for (int q = 0; q < 4; ++q) M3r[q] = mbuf[par][2][wq][q];
        const int npo = compact_row(lane, M3r, lst);
        const float2 os = sum_o_lds(lst, npo >> 3, ldsO, offBo);
        mo0 = __fadd_rn(__fmul_rn(Bo0, mo0), __fadd_rn(os.x, bo0));
        mo1 = __fadd_rn(__fmul_rn(Bo1, mo1), __fadd_rn(os.y, bo1));
    }

    #pragma unroll
    for (int r = 0; r < 4; ++r) {
        m1s[(size_t)(b0 + r) * Hh + hq] = m1a[r];
        m2s[(size_t)(b0 + r) * Hh + hq] = m2a[r];
        m3s[(size_t)(b0 + r) * Hh + hq] = m3a[r];
    }
    *(float2*)(mos + (size_t)brow * 128 + off2) = make_float2(mo0, mo1);

    float* dst = out + ((lane < 32) ? 0 : (size_t)Bsz * Oo) + (size_t)brow * Oo + oo;
    const float o0 = (float)(1.0 / (1.0 + exp(-(double)mo0)));
    const float o1 = (float)(1.0 / (1.0 + exp(-(double)mo1)));
    *(float2*)dst = make_float2(o0, o1);
}

// ---------------- layer-1 GEMM, register-tiled 4h x 8t per thread ----------
template<int TT>
__global__ __launch_bounds__(256) void gemm_l1_r8(
    const float* __restrict__ x, const float* __restrict__ Wt_in,
    const float* __restrict__ b_in, float* __restrict__ cur1,
    int tg_base, int TCloc)
{
    __shared__ float xs[Dd][TT];
    const int tid = threadIdx.x;
    const int b   = blockIdx.x;
    const int ty  = blockIdx.y;
    const int tg0 = tg_base + ty * TT;
    const float* xb = x + (size_t)b * Dd * Tt + tg0;
    constexpr int T4 = TT / 4;
    for (int v = tid; v < Dd * T4; v += 256) {
        const int d = v / T4, j4 = v - d * T4;
        *(float4*)&xs[d][j4 * 4] = *(const float4*)(xb + (size_t)d * Tt + j4 * 4);
    }
    __syncthreads();
    constexpr int TS = TT / 4;          // 8 t per thread
    const int hq = tid & 63;            // h base = 4*hq
    const int tq = tid >> 6;            // t base = TS*tq
    float c0[TS], c1[TS], c2[TS], c3[TS];
    #pragma unroll
    for (int j = 0; j < TS; ++j) { c0[j] = 0.f; c1[j] = 0.f; c2[j] = 0.f; c3[j] = 0.f; }
    const float* wp = Wt_in + hq * 4;
    float4 w = *(const float4*)(wp);
    #pragma unroll 4
    for (int d = 0; d < Dd; ++d) {
        float4 wn;
        if (d + 1 < Dd) wn = *(const float4*)(wp + (size_t)(d + 1) * Hh);  // prefetch
        #pragma unroll
        for (int j = 0; j < TS; ++j) {
            const float xv = xs[d][tq * TS + j];
            c0[j] = fmaf(w.x, xv, c0[j]);
            c1[j] = fmaf(w.y, xv, c1[j]);
            c2[j] = fmaf(w.z, xv, c2[j]);
            c3[j] = fmaf(w.w, xv, c3[j]);
        }
        w = wn;
    }
    const float4 bb = *(const float4*)(b_in + hq * 4);
    float* cb = cur1 + ((size_t)b * TCloc + ty * TT + tq * TS) * Hh + hq * 4;
    #pragma unroll
    for (int j = 0; j < TS; ++j) {
        float4 o;
        o.x = __fadd_rn(c0[j], bb.x);
        o.y = __fadd_rn(c1[j], bb.y);
        o.z = __fadd_rn(c2[j], bb.z);
        o.w = __fadd_rn(c3[j], bb.w);
        *(float4*)(cb + (size_t)j * Hh) = o;
    }
}

// ---- small-TC fallbacks (unchanged) ---------------------------------------
template<int TT>
__global__ __launch_bounds__(256) void gemm_l1_lds(
    const float* __restrict__ x, const float* __restrict__ Wt_in,
    const float* __restrict__ b_in, float* __restrict__ cur1,
    int tg_base, int TCloc)
{
    __shared__ float xs[Dd][TT];
    const int h   = threadIdx.x;
    const int b   = blockIdx.x;
    const int ty  = blockIdx.y;
    const int tg0 = tg_base + ty * TT;
    const float* xb = x + (size_t)b * Dd * Tt + tg0;
    constexpr int T4 = TT / 4;
    for (int v = threadIdx.x; v < Dd * T4; v += 256) {
        const int d = v / T4, j4 = v - d * T4;
        *(float4*)&xs[d][j4 * 4] = *(const float4*)(xb + (size_t)d * Tt + j4 * 4);
    }
    __syncthreads();
    float c[TT];
    #pragma unroll
    for (int j = 0; j < TT; ++j) c[j] = 0.f;
    for (int d = 0; d < Dd; ++d) {
        const float w = Wt_in[d * Hh + h];        // coalesced
        #pragma unroll
        for (int j = 0; j < TT; ++j) c[j] = fmaf(w, xs[d][j], c[j]);  // broadcast
    }
    const float bb = b_in[h];
    float* cb = cur1 + ((size_t)b * TCloc + ty * TT) * Hh;
    #pragma unroll
    for (int j = 0; j < TT; ++j) cb[j * Hh + h] = __fadd_rn(c[j], bb);
}

template<int TT>
__global__ __launch_bounds__(256) void gemm_l1_simple(
    const float* __restrict__ x, const float* __restrict__ Wt_in,
    const float* __restrict__ b_in, float* __restrict__ cur1, int tg0)
{
    const int h = threadIdx.x;
    const int b = blockIdx.x;
    float c[TT];
    #pragma unroll
    for (int j = 0; j < TT; ++j) c[j] = 0.f;
    const float* xb = x + (size_t)b * Dd * Tt + tg0;
    for (int d = 0; d < Dd; ++d) {
        const float w = Wt_in[d * Hh + h];
        const float* xp = xb + (size_t)d * Tt;
        #pragma unroll
        for (int j = 0; j < TT; ++j) c[j] = fmaf(w, xp[j], c[j]);
    }
    const float bb = b_in[h];
    float* cb = cur1 + (size_t)b * TT * Hh;
    #pragma unroll
    for (int j = 0; j < TT; ++j) cb[j * Hh + h] = __fadd_rn(c[j], bb);
}

} // namespace

extern "C" void kernel_launch(void* const* d_in, const int* in_sizes, int n_in,
                              void* d_out, int out_size, void* d_ws, size_t ws_size,
                              hipStream_t stream) {
    const float* x      = (const float*)d_in[0];
    const float* W_in   = (const float*)d_in[1];
    const float* b_in   = (const float*)d_in[2];
    const float* beta1  = (const float*)d_in[3];
    const float* thr1   = (const float*)d_in[4];
    const float* W_h    = (const float*)d_in[5];
    const float* b_h    = (const float*)d_in[6];
    const float* beta2  = (const float*)d_in[7];
    const float* thr2   = (const float*)d_in[8];
    const float* W_h1   = (const float*)d_in[9];
    const float* b_h1   = (const float*)d_in[10];
    const float* W_f    = (const float*)d_in[11];
    const float* b_f    = (const float*)d_in[12];
    const float* beta_f = (const float*)d_in[13];
    const float* W_a    = (const float*)d_in[14];
    const float* b_a    = (const float*)d_in[15];
    const float* beta_a = (const float*)d_in[16];
    float* out = (float*)d_out;

    float* ws = (float*)d_ws;
    size_t off = 0;
    auto alloc = [&](size_t n) { float* p = ws + off; off += n; return p; };
    float* Wt_in = alloc(257 * 256);
    float* Wt_h  = alloc(257 * 256);
    float* Wt_h1 = alloc(257 * 256);
    float* WtO   = alloc(257 * 128);
    float* m1s   = alloc((size_t)Bsz * Hh);
    float* m2s   = alloc((size_t)Bsz * Hh);
    float* m3s   = alloc((size_t)Bsz * Hh);
    float* mos   = alloc((size_t)Bsz * 128);
    const size_t fixed = off;

    int TC = 1;
    const int cands[8] = {128, 64, 32, 16, 8, 4, 2, 1};
    for (int i = 0; i < 8; ++i) {
        if ((fixed + (size_t)cands[i] * Bsz * Hh) * sizeof(float) <= ws_size) { TC = cands[i]; break; }
    }
    float* cur1 = alloc((size_t)TC * Bsz * Hh);

    pack_t<<<257, 256, 0, stream>>>(W_in, Wt_in, 256, 256);
    pack_t<<<257, 256, 0, stream>>>(W_h,  Wt_h,  256, 256);
    pack_t<<<257, 256, 0, stream>>>(W_h1, Wt_h1, 256, 256);
    pack_o<<<129, 256, 0, stream>>>(W_f, W_a, WtO);

    const int nch = Tt / TC;
    for (int c = 0; c < nch; ++c) {
        const int tg = c * TC;
        if (TC >= 32)
            gemm_l1_r8<32><<<dim3(Bsz, TC / 32), 256, 0, stream>>>(x, Wt_in, b_in, cur1, tg, TC);
        else if (TC == 16)
            gemm_l1_lds<16><<<dim3(Bsz, 1), 256, 0, stream>>>(x, Wt_in, b_in, cur1, tg, TC);
        else if (TC == 8)
            gemm_l1_lds<8><<<dim3(Bsz, 1), 256, 0, stream>>>(x, Wt_in, b_in, cur1, tg, TC);
        else if (TC == 4)
            gemm_l1_simple<4><<<Bsz, 256, 0, stream>>>(x, Wt_in, b_in, cur1, tg);
        else if (TC == 2)
            gemm_l1_simple<2><<<Bsz, 256, 0, stream>>>(x, Wt_in, b_in, cur1, tg);
        else
            gemm_l1_simple<1><<<Bsz, 256, 0, stream>>>(x, Wt_in, b_in, cur1, tg);

        snn_rec<<<Bsz / 4, 256, 0, stream>>>(
            cur1, Wt_h, Wt_h1, WtO,
            beta1, thr1, b_h, beta2, thr2, b_h1,
            b_f, beta_f, b_a, beta_a,
            m1s, m2s, m3s, mos, out, TC, (c == 0) ? 1 : 0);
    }
}

// Round 7
// 1207.011 us; speedup vs baseline: 2.0574x; 2.0574x over previous
//
#include <hip/hip_runtime.h>
#include <math.h>
#include <stdint.h>

// ---------------------------------------------------------------------------
// SNN forward — R14: exact R10 snn_rec (817us, best verified) + GEMM d-loop
// software-pipelined 1 iteration deep on BOTH operand streams (explicit
// float4 LDS reads -> ds_read_b128, w prefetch).
//
// Bit-exactness contract (R3..R13, absmax 4.882812e-4):
//   - layer-1: c=0; for d ascending: c=fmaf(w,x,c); then __fadd_rn(c,bias)
//   - spike layers: sum over spiking k ASCENDING, sequential __fadd_rn chain
//     seeded 0; sentinel k=256 hits zeroed row (c+0=c; c never -0)
//   - LIF: individually-rounded fp32 ops, reset from PREVIOUS mem
//
// R13 post-mortem: union gather regressed 817->2207us (VALUBusy 60%, 1.06M
// bank conflicts): rowmask conditional adds ~4x'd VALU on the serial chain
// and dword loads 4x'd load-issue count. Confirms snn_rec is saturated on
// the per-CU vector-load return path (~64B/clk): 2 layers x 4 rows x
// p*256KB ~ 860KB/step/CU at p~0.42 -> 6.4us/step -> 817us measured.
// Byte-sharing schemes all model at <=10% end-to-end gain with VALU/barrier
// costs. R14 banks R10 and closes GEMM: 290us vs 125us fma floor; R12
// showed w-prefetch alone = no change, so pipeline the xs (LDS) stream too.
// ---------------------------------------------------------------------------

namespace {

constexpr int Bsz = 1024;
constexpr int Dd  = 256;
constexpr int Tt  = 128;
constexpr int Hh  = 256;
constexpr int Oo  = 64;

// Wt[c*R + r] = W[r*C + c] for c<C; row c==C zeroed (sparse sentinel target).
__global__ void pack_t(const float* __restrict__ W, float* __restrict__ Wt,
                       int R, int C) {
    int idx = blockIdx.x * 256 + threadIdx.x;
    if (idx >= (C + 1) * R) return;
    int c = idx / R, r = idx - c * R;
    Wt[idx] = (c < C) ? W[(size_t)r * C + c] : 0.f;
}

// WtO[k*128 + o]: o<64 -> W_f[o][k], o>=64 -> W_a[o-64][k]; row k==256 zeroed.
__global__ void pack_o(const float* __restrict__ Wf, const float* __restrict__ Wa,
                       float* __restrict__ WtO) {
    int idx = blockIdx.x * 256 + threadIdx.x;
    if (idx >= 257 * 128) return;
    int k = idx >> 7, o = idx & 127;
    float v = 0.f;
    if (k < 256) v = (o < 64) ? Wf[(size_t)o * 256 + k] : Wa[(size_t)(o - 64) * 256 + k];
    WtO[idx] = v;
}

__device__ __forceinline__ float clamp01(float v) { return fminf(fmaxf(v, 0.f), 1.f); }

__device__ __forceinline__ bool lif_step(float& m, float cur, float B, float Th) {
    const float r = (__fsub_rn(m, Th) > 0.f) ? Th : 0.f;   // reset from PREVIOUS mem
    m = __fsub_rn(__fadd_rn(__fmul_rn(B, m), cur), r);
    return __fsub_rn(m, Th) > 0.f;
}

// Build 256-bit spike mask from 4 bits/lane (lane owns neurons 4L..4L+3):
// word q bit p = neuron 64q+p, contributed by lane 16q+(p>>2), bit (p&3).
__device__ __forceinline__ void make_masks(int nib, int lane, uint64_t* M) {
    #pragma unroll
    for (int q = 0; q < 4; ++q) {
        const int v   = __shfl(nib, 16 * q + (lane >> 2), 64);
        const int bit = (v >> (lane & 3)) & 1;
        M[q] = __ballot(bit != 0);
    }
}

// Branchless compaction: write ascending-neuron u16 index list to lst,
// pad to multiple of 8 with sentinel Hh. Returns npad (uniform).
__device__ __forceinline__ int compact(int nib, int lane, const uint64_t* M,
                                       uint16_t* lst) {
    const int p0 = (int)__popcll(M[0]);
    const int p1 = (int)__popcll(M[1]);
    const int p2 = (int)__popcll(M[2]);
    const int p3 = (int)__popcll(M[3]);
    const int q  = lane >> 4;
    const int base = ((q >= 1) ? p0 : 0) + ((q >= 2) ? p1 : 0) + ((q >= 3) ? p2 : 0);
    const uint64_t mq = (q & 2) ? ((q & 1) ? M[3] : M[2])
                                : ((q & 1) ? M[1] : M[0]);
    const int posb = (lane & 15) << 2;
    const int r0 = base + (int)__popcll(mq & ((1ull << posb) - 1ull));
    const int s1 = nib & 1;
    const int s2 = s1 + ((nib >> 1) & 1);
    const int s3 = s2 + ((nib >> 2) & 1);
    const int nb = lane << 2;
    if (nib & 1) lst[r0]      = (uint16_t)nb;
    if (nib & 2) lst[r0 + s1] = (uint16_t)(nb + 1);
    if (nib & 4) lst[r0 + s2] = (uint16_t)(nb + 2);
    if (nib & 8) lst[r0 + s3] = (uint16_t)(nb + 3);
    const int n    = p0 + p1 + p2 + p3;
    const int npad = (n + 7) & ~7;
    if (lane < npad - n) lst[n + lane] = (uint16_t)Hh;
    return npad;
}

// ---- hidden-layer gather: 8 dwordx4 loads per batch, depth-3 pipeline -----

__device__ __forceinline__ void issue8h(const char* __restrict__ tab,
                                        uint4 I, int offB, float4* w) {
    const int k[8] = {(int)(I.x & 0xffff), (int)(I.x >> 16),
                      (int)(I.y & 0xffff), (int)(I.y >> 16),
                      (int)(I.z & 0xffff), (int)(I.z >> 16),
                      (int)(I.w & 0xffff), (int)(I.w >> 16)};
    #pragma unroll
    for (int i = 0; i < 8; ++i)
        w[i] = *(const float4*)(tab + (k[i] << 10) + offB);
}

__device__ __forceinline__ void cons8h(float4& c, const float4* w) {
    #pragma unroll
    for (int i = 0; i < 8; ++i) {
        c.x = __fadd_rn(c.x, w[i].x);
        c.y = __fadd_rn(c.y, w[i].y);
        c.z = __fadd_rn(c.z, w[i].z);
        c.w = __fadd_rn(c.w, w[i].w);
    }
}

// Depth-3 rotation, consume order ascending (bit-exact). sched_barrier(0)
// after each issue group pins the rotation against scheduler collapse (R8).
__device__ __forceinline__ float4 sum_h(const uint16_t* lst, int nbat,
                                        const float* __restrict__ tab, int offB) {
    float4 c = {0.f, 0.f, 0.f, 0.f};
    if (nbat == 0) return c;
    const char* tb = (const char*)tab;
    float4 A[8], B[8], C[8];
    issue8h(tb, *(const uint4*)(lst), offB, A);
    if (nbat == 1) { cons8h(c, A); return c; }
    issue8h(tb, *(const uint4*)(lst + 8), offB, B);
    if (nbat == 2) { cons8h(c, A); cons8h(c, B); return c; }
    issue8h(tb, *(const uint4*)(lst + 16), offB, C);
    __builtin_amdgcn_sched_barrier(0);
    int i = 3;
    for (; i + 2 < nbat; i += 3) {
        cons8h(c, A); issue8h(tb, *(const uint4*)(lst + 8 * i), offB, A);
        __builtin_amdgcn_sched_barrier(0);
        cons8h(c, B); issue8h(tb, *(const uint4*)(lst + 8 * (i + 1)), offB, B);
        __builtin_amdgcn_sched_barrier(0);
        cons8h(c, C); issue8h(tb, *(const uint4*)(lst + 8 * (i + 2)), offB, C);
        __builtin_amdgcn_sched_barrier(0);
    }
    const int r = nbat - i;
    if (r == 0) {
        cons8h(c, A); cons8h(c, B); cons8h(c, C);
    } else if (r == 1) {
        cons8h(c, A); issue8h(tb, *(const uint4*)(lst + 8 * i), offB, A);
        cons8h(c, B); cons8h(c, C); cons8h(c, A);
    } else {
        cons8h(c, A); issue8h(tb, *(const uint4*)(lst + 8 * i), offB, A);
        cons8h(c, B); issue8h(tb, *(const uint4*)(lst + 8 * (i + 1)), offB, B);
        cons8h(c, C); cons8h(c, A); cons8h(c, B);
    }
    return c;
}

// ---- output-layer gather from LDS-resident WtO (ds_read_b64, ~free banks) -

__device__ __forceinline__ float2 sum_o_lds(const uint16_t* lst, int nbat,
                                            const float* tab, int offB) {
    float2 c = {0.f, 0.f};
    const char* tb = (const char*)tab;
    for (int i = 0; i < nbat; ++i) {
        const uint4 I = *(const uint4*)(lst + 8 * i);
        float2 w[8];
        w[0] = *(const float2*)(tb + ((I.x & 0xffffu) << 9) + offB);
        w[1] = *(const float2*)(tb + ((I.x >> 16)    << 9) + offB);
        w[2] = *(const float2*)(tb + ((I.y & 0xffffu) << 9) + offB);
        w[3] = *(const float2*)(tb + ((I.y >> 16)    << 9) + offB);
        w[4] = *(const float2*)(tb + ((I.z & 0xffffu) << 9) + offB);
        w[5] = *(const float2*)(tb + ((I.z >> 16)    << 9) + offB);
        w[6] = *(const float2*)(tb + ((I.w & 0xffffu) << 9) + offB);
        w[7] = *(const float2*)(tb + ((I.w >> 16)    << 9) + offB);
        #pragma unroll
        for (int j = 0; j < 8; ++j) {
            c.x = __fadd_rn(c.x, w[j].x);
            c.y = __fadd_rn(c.y, w[j].y);
        }
    }
    return c;
}

// ---------------- recurrent kernel: one WAVE per batch row -----------------
// 256 threads = 4 independent waves, per-wave LDS lists; the only barrier is
// the one-time WtO staging sync before the t-loop. (Exact R10 form, 817us.)
__global__ __launch_bounds__(256, 1) void snn_rec(
    const float* __restrict__ cur1,     // [b][t_local][h]
    const float* __restrict__ Wt_h, const float* __restrict__ Wt_h1,
    const float* __restrict__ WtO,
    const float* __restrict__ beta1, const float* __restrict__ thr1,
    const float* __restrict__ b_h,  const float* __restrict__ beta2, const float* __restrict__ thr2,
    const float* __restrict__ b_h1,
    const float* __restrict__ b_f,  const float* __restrict__ beta_f,
    const float* __restrict__ b_a,  const float* __restrict__ beta_a,
    float* __restrict__ m1s, float* __restrict__ m2s, float* __restrict__ m3s,
    float* __restrict__ mos, float* __restrict__ out,
    int TC, int first)
{
    __shared__ __attribute__((aligned(16))) float ldsO[257 * 128];   // 128.5 KB
    __shared__ __attribute__((aligned(16))) uint16_t lists[4][272];

    const int tid  = threadIdx.x;
    const int lane = tid & 63;
    const int b    = blockIdx.x * 4 + (tid >> 6);
    uint16_t* lst  = lists[tid >> 6];
    const int off4 = lane * 4;          // hidden neuron base 4L
    const int off2 = lane * 2;          // output slot base 2L
    const int offBh = lane * 16;        // byte offset into 1KB hidden rows
    const int offBo = lane * 8;         // byte offset into 512B output rows

    // ---- stage WtO into LDS (one-time; bit-identical values) --------------
    {
        const float4* s4 = (const float4*)WtO;
        float4* d4 = (float4*)ldsO;
        for (int v = tid; v < (257 * 128) / 4; v += 256) d4[v] = s4[v];
    }
    __syncthreads();

    const float4 B1v  = *(const float4*)(beta1 + off4);
    const float4 Th1v = *(const float4*)(thr1  + off4);
    const float4 bhv  = *(const float4*)(b_h   + off4);
    const float4 B2v  = *(const float4*)(beta2 + off4);
    const float4 Th2v = *(const float4*)(thr2  + off4);
    const float4 bh1v = *(const float4*)(b_h1  + off4);
    const float4 B1c  = {clamp01(B1v.x), clamp01(B1v.y), clamp01(B1v.z), clamp01(B1v.w)};
    const float4 B2c  = {clamp01(B2v.x), clamp01(B2v.y), clamp01(B2v.z), clamp01(B2v.w)};

    const int oo = off2 & 63;
    const float* bop = (lane < 32) ? b_f    : b_a;
    const float* Bop = (lane < 32) ? beta_f : beta_a;
    const float bo0 = bop[oo], bo1 = bop[oo + 1];
    const float Bo0 = clamp01(Bop[oo]), Bo1 = clamp01(Bop[oo + 1]);

    float4 m1, m2, m3;
    float mo0, mo1;
    if (first) {
        m1 = m2 = m3 = make_float4(0.f, 0.f, 0.f, 0.f);
        mo0 = mo1 = 0.f;
    } else {
        m1 = *(const float4*)(m1s + (size_t)b * Hh + off4);
        m2 = *(const float4*)(m2s + (size_t)b * Hh + off4);
        m3 = *(const float4*)(m3s + (size_t)b * Hh + off4);
        const float2 mo = *(const float2*)(mos + (size_t)b * 128 + off2);
        mo0 = mo.x; mo1 = mo.y;
    }

    const float* __restrict__ curb = cur1 + (size_t)b * TC * Hh + off4;
    float4 cur = *(const float4*)(curb);
    uint64_t M[4];

    for (int t = 0; t < TC; ++t) {
        // ---- layer 1 (cur precomputed by GEMM, bias included) -------------
        int nib = 0;
        nib |= (int)lif_step(m1.x, cur.x, B1c.x, Th1v.x);
        nib |= (int)lif_step(m1.y, cur.y, B1c.y, Th1v.y) << 1;
        nib |= (int)lif_step(m1.z, cur.z, B1c.z, Th1v.z) << 2;
        nib |= (int)lif_step(m1.w, cur.w, B1c.w, Th1v.w) << 3;
        make_masks(nib, lane, M);
        int npad = compact(nib, lane, M, lst);
        if (t + 1 < TC) cur = *(const float4*)(curb + (size_t)(t + 1) * Hh);  // prefetch

        // ---- layer 2 ------------------------------------------------------
        float4 s = sum_h(lst, npad >> 3, Wt_h, offBh);
        nib  = (int)lif_step(m2.x, __fadd_rn(s.x, bhv.x), B2c.x, Th2v.x);
        nib |= (int)lif_step(m2.y, __fadd_rn(s.y, bhv.y), B2c.y, Th2v.y) << 1;
        nib |= (int)lif_step(m2.z, __fadd_rn(s.z, bhv.z), B2c.z, Th2v.z) << 2;
        nib |= (int)lif_step(m2.w, __fadd_rn(s.w, bhv.w), B2c.w, Th2v.w) << 3;
        make_masks(nib, lane, M);
        npad = compact(nib, lane, M, lst);

        // ---- layer 3 (reuses beta2/thr2 — source bug preserved) ----------
        s = sum_h(lst, npad >> 3, Wt_h1, offBh);
        nib  = (int)lif_step(m3.x, __fadd_rn(s.x, bh1v.x), B2c.x, Th2v.x);
        nib |= (int)lif_step(m3.y, __fadd_rn(s.y, bh1v.y), B2c.y, Th2v.y) << 1;
        nib |= (int)lif_step(m3.z, __fadd_rn(s.z, bh1v.z), B2c.z, Th2v.z) << 2;
        nib |= (int)lif_step(m3.w, __fadd_rn(s.w, bh1v.w), B2c.w, Th2v.w) << 3;
        make_masks(nib, lane, M);
        npad = compact(nib, lane, M, lst);

        // ---- output LI neurons (no reset), gather from LDS ---------------
        const float2 os = sum_o_lds(lst, npad >> 3, ldsO, offBo);
        mo0 = __fadd_rn(__fmul_rn(Bo0, mo0), __fadd_rn(os.x, bo0));
        mo1 = __fadd_rn(__fmul_rn(Bo1, mo1), __fadd_rn(os.y, bo1));
    }

    *(float4*)(m1s + (size_t)b * Hh + off4) = m1;
    *(float4*)(m2s + (size_t)b * Hh + off4) = m2;
    *(float4*)(m3s + (size_t)b * Hh + off4) = m3;
    *(float2*)(mos + (size_t)b * 128 + off2) = make_float2(mo0, mo1);

    float* dst = out + ((lane < 32) ? 0 : (size_t)Bsz * Oo) + (size_t)b * Oo + oo;
    const float o0 = (float)(1.0 / (1.0 + exp(-(double)mo0)));
    const float o1 = (float)(1.0 / (1.0 + exp(-(double)mo1)));
    *(float2*)dst = make_float2(o0, o1);
}

// ---------------- layer-1 GEMM, R14: d-loop pipelined 1 deep ---------------
// Block: 256 threads = 64 h-quads x 4 t-groups; TT=32 t-columns per block.
// Per d: 1 float4 w-load + 2 explicit float4 LDS reads (ds_read_b128), all
// prefetched one d ahead so 32 fmas sit between load and use.
// Bit-exact: per (h,t) c is a sequential fmaf chain over d ascending.
template<int TT>
__global__ __launch_bounds__(256) void gemm_l1_r14(
    const float* __restrict__ x, const float* __restrict__ Wt_in,
    const float* __restrict__ b_in, float* __restrict__ cur1,
    int tg_base, int TCloc)
{
    __shared__ float xs[Dd][TT];
    const int tid = threadIdx.x;
    const int b   = blockIdx.x;
    const int ty  = blockIdx.y;
    const int tg0 = tg_base + ty * TT;
    const float* xb = x + (size_t)b * Dd * Tt + tg0;
    constexpr int T4 = TT / 4;
    for (int v = tid; v < Dd * T4; v += 256) {
        const int d = v / T4, j4 = v - d * T4;
        *(float4*)&xs[d][j4 * 4] = *(const float4*)(xb + (size_t)d * Tt + j4 * 4);
    }
    __syncthreads();
    constexpr int TS = TT / 4;          // 8 t per thread
    const int hq = tid & 63;            // h base = 4*hq
    const int tq = tid >> 6;            // t base = TS*tq
    float c0[TS], c1[TS], c2[TS], c3[TS];
    #pragma unroll
    for (int j = 0; j < TS; ++j) { c0[j] = 0.f; c1[j] = 0.f; c2[j] = 0.f; c3[j] = 0.f; }
    const float* wp = Wt_in + hq * 4;
    const float* xr = &xs[0][tq * TS];
    float4 w  = *(const float4*)(wp);
    float4 xa = *(const float4*)(xr);
    float4 xq = *(const float4*)(xr + 4);
    #pragma unroll 2
    for (int d = 0; d < Dd; ++d) {
        float4 wn, xan, xqn;
        const bool more = (d + 1 < Dd);
        if (more) {
            wn  = *(const float4*)(wp + (size_t)(d + 1) * Hh);
            xan = *(const float4*)(xr + (size_t)(d + 1) * TT);
            xqn = *(const float4*)(xr + (size_t)(d + 1) * TT + 4);
        }
        const float xv[8] = {xa.x, xa.y, xa.z, xa.w, xq.x, xq.y, xq.z, xq.w};
        #pragma unroll
        for (int j = 0; j < TS; ++j) {
            c0[j] = fmaf(w.x, xv[j], c0[j]);
            c1[j] = fmaf(w.y, xv[j], c1[j]);
            c2[j] = fmaf(w.z, xv[j], c2[j]);
            c3[j] = fmaf(w.w, xv[j], c3[j]);
        }
        if (more) { w = wn; xa = xan; xq = xqn; }
    }
    const float4 bb = *(const float4*)(b_in + hq * 4);
    float* cb = cur1 + ((size_t)b * TCloc + ty * TT + tq * TS) * Hh + hq * 4;
    #pragma unroll
    for (int j = 0; j < TS; ++j) {
        float4 o;
        o.x = __fadd_rn(c0[j], bb.x);
        o.y = __fadd_rn(c1[j], bb.y);
        o.z = __fadd_rn(c2[j], bb.z);
        o.w = __fadd_rn(c3[j], bb.w);
        *(float4*)(cb + (size_t)j * Hh) = o;
    }
}

// ---- small-TC fallbacks (unchanged) ---------------------------------------
template<int TT>
__global__ __launch_bounds__(256) void gemm_l1_lds(
    const float* __restrict__ x, const float* __restrict__ Wt_in,
    const float* __restrict__ b_in, float* __restrict__ cur1,
    int tg_base, int TCloc)
{
    __shared__ float xs[Dd][TT];
    const int h   = threadIdx.x;
    const int b   = blockIdx.x;
    const int ty  = blockIdx.y;
    const int tg0 = tg_base + ty * TT;
    const float* xb = x + (size_t)b * Dd * Tt + tg0;
    constexpr int T4 = TT / 4;
    for (int v = threadIdx.x; v < Dd * T4; v += 256) {
        const int d = v / T4, j4 = v - d * T4;
        *(float4*)&xs[d][j4 * 4] = *(const float4*)(xb + (size_t)d * Tt + j4 * 4);
    }
    __syncthreads();
    float c[TT];
    #pragma unroll
    for (int j = 0; j < TT; ++j) c[j] = 0.f;
    for (int d = 0; d < Dd; ++d) {
        const float w = Wt_in[d * Hh + h];        // coalesced
        #pragma unroll
        for (int j = 0; j < TT; ++j) c[j] = fmaf(w, xs[d][j], c[j]);  // broadcast
    }
    const float bb = b_in[h];
    float* cb = cur1 + ((size_t)b * TCloc + ty * TT) * Hh;
    #pragma unroll
    for (int j = 0; j < TT; ++j) cb[j * Hh + h] = __fadd_rn(c[j], bb);
}

template<int TT>
__global__ __launch_bounds__(256) void gemm_l1_simple(
    const float* __restrict__ x, const float* __restrict__ Wt_in,
    const float* __restrict__ b_in, float* __restrict__ cur1, int tg0)
{
    const int h = threadIdx.x;
    const int b = blockIdx.x;
    float c[TT];
    #pragma unroll
    for (int j = 0; j < TT; ++j) c[j] = 0.f;
    const float* xb = x + (size_t)b * Dd * Tt + tg0;
    for (int d = 0; d < Dd; ++d) {
        const float w = Wt_in[d * Hh + h];
        const float* xp = xb + (size_t)d * Tt;
        #pragma unroll
        for (int j = 0; j < TT; ++j) c[j] = fmaf(w, xp[j], c[j]);
    }
    const float bb = b_in[h];
    float* cb = cur1 + (size_t)b * TT * Hh;
    #pragma unroll
    for (int j = 0; j < TT; ++j) cb[j * Hh + h] = __fadd_rn(c[j], bb);
}

} // namespace

extern "C" void kernel_launch(void* const* d_in, const int* in_sizes, int n_in,
                              void* d_out, int out_size, void* d_ws, size_t ws_size,
                              hipStream_t stream) {
    const float* x      = (const float*)d_in[0];
    const float* W_in   = (const float*)d_in[1];
    const float* b_in   = (const float*)d_in[2];
    const float* beta1  = (const float*)d_in[3];
    const float* thr1   = (const float*)d_in[4];
    const float* W_h    = (const float*)d_in[5];
    const float* b_h    = (const float*)d_in[6];
    const float* beta2  = (const float*)d_in[7];
    const float* thr2   = (const float*)d_in[8];
    const float* W_h1   = (const float*)d_in[9];
    const float* b_h1   = (const float*)d_in[10];
    const float* W_f    = (const float*)d_in[11];
    const float* b_f    = (const float*)d_in[12];
    const float* beta_f = (const float*)d_in[13];
    const float* W_a    = (const float*)d_in[14];
    const float* b_a    = (const float*)d_in[15];
    const float* beta_a = (const float*)d_in[16];
    float* out = (float*)d_out;

    float* ws = (float*)d_ws;
    size_t off = 0;
    auto alloc = [&](size_t n) { float* p = ws + off; off += n; return p; };
    float* Wt_in = alloc(257 * 256);
    float* Wt_h  = alloc(257 * 256);
    float* Wt_h1 = alloc(257 * 256);
    float* WtO   = alloc(257 * 128);
    float* m1s   = alloc((size_t)Bsz * Hh);
    float* m2s   = alloc((size_t)Bsz * Hh);
    float* m3s   = alloc((size_t)Bsz * Hh);
    float* mos   = alloc((size_t)Bsz * 128);
    const size_t fixed = off;

    int TC = 1;
    const int cands[8] = {128, 64, 32, 16, 8, 4, 2, 1};
    for (int i = 0; i < 8; ++i) {
        if ((fixed + (size_t)cands[i] * Bsz * Hh) * sizeof(float) <= ws_size) { TC = cands[i]; break; }
    }
    float* cur1 = alloc((size_t)TC * Bsz * Hh);

    pack_t<<<257, 256, 0, stream>>>(W_in, Wt_in, 256, 256);
    pack_t<<<257, 256, 0, stream>>>(W_h,  Wt_h,  256, 256);
    pack_t<<<257, 256, 0, stream>>>(W_h1, Wt_h1, 256, 256);
    pack_o<<<129, 256, 0, stream>>>(W_f, W_a, WtO);

    const int nch = Tt / TC;
    for (int c = 0; c < nch; ++c) {
        const int tg = c * TC;
        if (TC >= 32)
            gemm_l1_r14<32><<<dim3(Bsz, TC / 32), 256, 0, stream>>>(x, Wt_in, b_in, cur1, tg, TC);
        else if (TC == 16)
            gemm_l1_lds<16><<<dim3(Bsz, 1), 256, 0, stream>>>(x, Wt_in, b_in, cur1, tg, TC);
        else if (TC == 8)
            gemm_l1_lds<8><<<dim3(Bsz, 1), 256, 0, stream>>>(x, Wt_in, b_in, cur1, tg, TC);
        else if (TC == 4)
            gemm_l1_simple<4><<<Bsz, 256, 0, stream>>>(x, Wt_in, b_in, cur1, tg);
        else if (TC == 2)
            gemm_l1_simple<2><<<Bsz, 256, 0, stream>>>(x, Wt_in, b_in, cur1, tg);
        else
            gemm_l1_simple<1><<<Bsz, 256, 0, stream>>>(x, Wt_in, b_in, cur1, tg);

        snn_rec<<<Bsz / 4, 256, 0, stream>>>(
            cur1, Wt_h, Wt_h1, WtO,
            beta1, thr1, b_h, beta2, thr2, b_h1,
            b_f, beta_f, b_a, beta_a,
            m1s, m2s, m3s, mos, out, TC, (c == 0) ? 1 : 0);
    }
}

// Round 8
// 1161.628 us; speedup vs baseline: 2.1377x; 1.0391x over previous
//
#include <hip/hip_runtime.h>
#include <math.h>
#include <stdint.h>

// ---------------------------------------------------------------------------
// SNN forward — R15: bank the best measured combination.
//   snn_rec : R10 form (WtO-in-LDS sum_o + depth-3 pinned sum_h) — 810.9us
//   GEMM    : R12 r8 form (4h x 8t register tile + 1-deep w prefetch) — ~290us
// No new mechanisms; pure recombination of verified-best components.
//
// Bit-exactness contract (R3..R14, absmax 4.882812e-4):
//   - layer-1: c=0; for d ascending: c=fmaf(w,x,c); then __fadd_rn(c,bias)
//   - spike layers: sum over spiking k ASCENDING, sequential __fadd_rn chain
//     seeded 0; sentinel k=256 hits zeroed row (c+0=c; c never -0)
//   - LIF: individually-rounded fp32 ops, reset from PREVIOUS mem
//
// Session summary (snn_rec): R7 980 -> R10 817 (WtO->LDS + depth-3) = best.
// Falsified alternatives: R8 depth-4 unpinned (collapse), R9 2-wave split
// (+50%), R11 depth-6 (VGPR cap spill, 5.2GB scratch), R12 depth-4 (+14%),
// R13 union gather (+170%). snn_rec is at the per-CU vector-load return
// path: 2 layers x 4 rows x p*256KB ~ 860KB/step/CU at p~0.42 -> 6.4us/step
// -> 819us model vs 811us measured. GEMM: R14 dual-stream pipeline regressed
// (~+90us); R12 r8+prefetch is the best measured (~290-300us, ~36% fp32
// peak); limiter is not operand latency (both scheduling attacks failed).
// ---------------------------------------------------------------------------

namespace {

constexpr int Bsz = 1024;
constexpr int Dd  = 256;
constexpr int Tt  = 128;
constexpr int Hh  = 256;
constexpr int Oo  = 64;

// Wt[c*R + r] = W[r*C + c] for c<C; row c==C zeroed (sparse sentinel target).
__global__ void pack_t(const float* __restrict__ W, float* __restrict__ Wt,
                       int R, int C) {
    int idx = blockIdx.x * 256 + threadIdx.x;
    if (idx >= (C + 1) * R) return;
    int c = idx / R, r = idx - c * R;
    Wt[idx] = (c < C) ? W[(size_t)r * C + c] : 0.f;
}

// WtO[k*128 + o]: o<64 -> W_f[o][k], o>=64 -> W_a[o-64][k]; row k==256 zeroed.
__global__ void pack_o(const float* __restrict__ Wf, const float* __restrict__ Wa,
                       float* __restrict__ WtO) {
    int idx = blockIdx.x * 256 + threadIdx.x;
    if (idx >= 257 * 128) return;
    int k = idx >> 7, o = idx & 127;
    float v = 0.f;
    if (k < 256) v = (o < 64) ? Wf[(size_t)o * 256 + k] : Wa[(size_t)(o - 64) * 256 + k];
    WtO[idx] = v;
}

__device__ __forceinline__ float clamp01(float v) { return fminf(fmaxf(v, 0.f), 1.f); }

__device__ __forceinline__ bool lif_step(float& m, float cur, float B, float Th) {
    const float r = (__fsub_rn(m, Th) > 0.f) ? Th : 0.f;   // reset from PREVIOUS mem
    m = __fsub_rn(__fadd_rn(__fmul_rn(B, m), cur), r);
    return __fsub_rn(m, Th) > 0.f;
}

// Build 256-bit spike mask from 4 bits/lane (lane owns neurons 4L..4L+3):
// word q bit p = neuron 64q+p, contributed by lane 16q+(p>>2), bit (p&3).
__device__ __forceinline__ void make_masks(int nib, int lane, uint64_t* M) {
    #pragma unroll
    for (int q = 0; q < 4; ++q) {
        const int v   = __shfl(nib, 16 * q + (lane >> 2), 64);
        const int bit = (v >> (lane & 3)) & 1;
        M[q] = __ballot(bit != 0);
    }
}

// Branchless compaction: write ascending-neuron u16 index list to lst,
// pad to multiple of 8 with sentinel Hh. Returns npad (uniform).
__device__ __forceinline__ int compact(int nib, int lane, const uint64_t* M,
                                       uint16_t* lst) {
    const int p0 = (int)__popcll(M[0]);
    const int p1 = (int)__popcll(M[1]);
    const int p2 = (int)__popcll(M[2]);
    const int p3 = (int)__popcll(M[3]);
    const int q  = lane >> 4;
    const int base = ((q >= 1) ? p0 : 0) + ((q >= 2) ? p1 : 0) + ((q >= 3) ? p2 : 0);
    const uint64_t mq = (q & 2) ? ((q & 1) ? M[3] : M[2])
                                : ((q & 1) ? M[1] : M[0]);
    const int posb = (lane & 15) << 2;
    const int r0 = base + (int)__popcll(mq & ((1ull << posb) - 1ull));
    const int s1 = nib & 1;
    const int s2 = s1 + ((nib >> 1) & 1);
    const int s3 = s2 + ((nib >> 2) & 1);
    const int nb = lane << 2;
    if (nib & 1) lst[r0]      = (uint16_t)nb;
    if (nib & 2) lst[r0 + s1] = (uint16_t)(nb + 1);
    if (nib & 4) lst[r0 + s2] = (uint16_t)(nb + 2);
    if (nib & 8) lst[r0 + s3] = (uint16_t)(nb + 3);
    const int n    = p0 + p1 + p2 + p3;
    const int npad = (n + 7) & ~7;
    if (lane < npad - n) lst[n + lane] = (uint16_t)Hh;
    return npad;
}

// ---- hidden-layer gather: 8 dwordx4 loads per batch, depth-3 pipeline -----

__device__ __forceinline__ void issue8h(const char* __restrict__ tab,
                                        uint4 I, int offB, float4* w) {
    const int k[8] = {(int)(I.x & 0xffff), (int)(I.x >> 16),
                      (int)(I.y & 0xffff), (int)(I.y >> 16),
                      (int)(I.z & 0xffff), (int)(I.z >> 16),
                      (int)(I.w & 0xffff), (int)(I.w >> 16)};
    #pragma unroll
    for (int i = 0; i < 8; ++i)
        w[i] = *(const float4*)(tab + (k[i] << 10) + offB);
}

__device__ __forceinline__ void cons8h(float4& c, const float4* w) {
    #pragma unroll
    for (int i = 0; i < 8; ++i) {
        c.x = __fadd_rn(c.x, w[i].x);
        c.y = __fadd_rn(c.y, w[i].y);
        c.z = __fadd_rn(c.z, w[i].z);
        c.w = __fadd_rn(c.w, w[i].w);
    }
}

// Depth-3 rotation, consume order ascending (bit-exact). sched_barrier(0)
// after each issue group pins the rotation against scheduler collapse (R8).
__device__ __forceinline__ float4 sum_h(const uint16_t* lst, int nbat,
                                        const float* __restrict__ tab, int offB) {
    float4 c = {0.f, 0.f, 0.f, 0.f};
    if (nbat == 0) return c;
    const char* tb = (const char*)tab;
    float4 A[8], B[8], C[8];
    issue8h(tb, *(const uint4*)(lst), offB, A);
    if (nbat == 1) { cons8h(c, A); return c; }
    issue8h(tb, *(const uint4*)(lst + 8), offB, B);
    if (nbat == 2) { cons8h(c, A); cons8h(c, B); return c; }
    issue8h(tb, *(const uint4*)(lst + 16), offB, C);
    __builtin_amdgcn_sched_barrier(0);
    int i = 3;
    for (; i + 2 < nbat; i += 3) {
        cons8h(c, A); issue8h(tb, *(const uint4*)(lst + 8 * i), offB, A);
        __builtin_amdgcn_sched_barrier(0);
        cons8h(c, B); issue8h(tb, *(const uint4*)(lst + 8 * (i + 1)), offB, B);
        __builtin_amdgcn_sched_barrier(0);
        cons8h(c, C); issue8h(tb, *(const uint4*)(lst + 8 * (i + 2)), offB, C);
        __builtin_amdgcn_sched_barrier(0);
    }
    const int r = nbat - i;
    if (r == 0) {
        cons8h(c, A); cons8h(c, B); cons8h(c, C);
    } else if (r == 1) {
        cons8h(c, A); issue8h(tb, *(const uint4*)(lst + 8 * i), offB, A);
        cons8h(c, B); cons8h(c, C); cons8h(c, A);
    } else {
        cons8h(c, A); issue8h(tb, *(const uint4*)(lst + 8 * i), offB, A);
        cons8h(c, B); issue8h(tb, *(const uint4*)(lst + 8 * (i + 1)), offB, B);
        cons8h(c, C); cons8h(c, A); cons8h(c, B);
    }
    return c;
}

// ---- output-layer gather from LDS-resident WtO (ds_read_b64, ~free banks) -

__device__ __forceinline__ float2 sum_o_lds(const uint16_t* lst, int nbat,
                                            const float* tab, int offB) {
    float2 c = {0.f, 0.f};
    const char* tb = (const char*)tab;
    for (int i = 0; i < nbat; ++i) {
        const uint4 I = *(const uint4*)(lst + 8 * i);
        float2 w[8];
        w[0] = *(const float2*)(tb + ((I.x & 0xffffu) << 9) + offB);
        w[1] = *(const float2*)(tb + ((I.x >> 16)    << 9) + offB);
        w[2] = *(const float2*)(tb + ((I.y & 0xffffu) << 9) + offB);
        w[3] = *(const float2*)(tb + ((I.y >> 16)    << 9) + offB);
        w[4] = *(const float2*)(tb + ((I.z & 0xffffu) << 9) + offB);
        w[5] = *(const float2*)(tb + ((I.z >> 16)    << 9) + offB);
        w[6] = *(const float2*)(tb + ((I.w & 0xffffu) << 9) + offB);
        w[7] = *(const float2*)(tb + ((I.w >> 16)    << 9) + offB);
        #pragma unroll
        for (int j = 0; j < 8; ++j) {
            c.x = __fadd_rn(c.x, w[j].x);
            c.y = __fadd_rn(c.y, w[j].y);
        }
    }
    return c;
}

// ---------------- recurrent kernel: one WAVE per batch row -----------------
// 256 threads = 4 independent waves, per-wave LDS lists; the only barrier is
// the one-time WtO staging sync before the t-loop. (Exact R10 form, 811us.)
__global__ __launch_bounds__(256, 1) void snn_rec(
    const float* __restrict__ cur1,     // [b][t_local][h]
    const float* __restrict__ Wt_h, const float* __restrict__ Wt_h1,
    const float* __restrict__ WtO,
    const float* __restrict__ beta1, const float* __restrict__ thr1,
    const float* __restrict__ b_h,  const float* __restrict__ beta2, const float* __restrict__ thr2,
    const float* __restrict__ b_h1,
    const float* __restrict__ b_f,  const float* __restrict__ beta_f,
    const float* __restrict__ b_a,  const float* __restrict__ beta_a,
    float* __restrict__ m1s, float* __restrict__ m2s, float* __restrict__ m3s,
    float* __restrict__ mos, float* __restrict__ out,
    int TC, int first)
{
    __shared__ __attribute__((aligned(16))) float ldsO[257 * 128];   // 128.5 KB
    __shared__ __attribute__((aligned(16))) uint16_t lists[4][272];

    const int tid  = threadIdx.x;
    const int lane = tid & 63;
    const int b    = blockIdx.x * 4 + (tid >> 6);
    uint16_t* lst  = lists[tid >> 6];
    const int off4 = lane * 4;          // hidden neuron base 4L
    const int off2 = lane * 2;          // output slot base 2L
    const int offBh = lane * 16;        // byte offset into 1KB hidden rows
    const int offBo = lane * 8;         // byte offset into 512B output rows

    // ---- stage WtO into LDS (one-time; bit-identical values) --------------
    {
        const float4* s4 = (const float4*)WtO;
        float4* d4 = (float4*)ldsO;
        for (int v = tid; v < (257 * 128) / 4; v += 256) d4[v] = s4[v];
    }
    __syncthreads();

    const float4 B1v  = *(const float4*)(beta1 + off4);
    const float4 Th1v = *(const float4*)(thr1  + off4);
    const float4 bhv  = *(const float4*)(b_h   + off4);
    const float4 B2v  = *(const float4*)(beta2 + off4);
    const float4 Th2v = *(const float4*)(thr2  + off4);
    const float4 bh1v = *(const float4*)(b_h1  + off4);
    const float4 B1c  = {clamp01(B1v.x), clamp01(B1v.y), clamp01(B1v.z), clamp01(B1v.w)};
    const float4 B2c  = {clamp01(B2v.x), clamp01(B2v.y), clamp01(B2v.z), clamp01(B2v.w)};

    const int oo = off2 & 63;
    const float* bop = (lane < 32) ? b_f    : b_a;
    const float* Bop = (lane < 32) ? beta_f : beta_a;
    const float bo0 = bop[oo], bo1 = bop[oo + 1];
    const float Bo0 = clamp01(Bop[oo]), Bo1 = clamp01(Bop[oo + 1]);

    float4 m1, m2, m3;
    float mo0, mo1;
    if (first) {
        m1 = m2 = m3 = make_float4(0.f, 0.f, 0.f, 0.f);
        mo0 = mo1 = 0.f;
    } else {
        m1 = *(const float4*)(m1s + (size_t)b * Hh + off4);
        m2 = *(const float4*)(m2s + (size_t)b * Hh + off4);
        m3 = *(const float4*)(m3s + (size_t)b * Hh + off4);
        const float2 mo = *(const float2*)(mos + (size_t)b * 128 + off2);
        mo0 = mo.x; mo1 = mo.y;
    }

    const float* __restrict__ curb = cur1 + (size_t)b * TC * Hh + off4;
    float4 cur = *(const float4*)(curb);
    uint64_t M[4];

    for (int t = 0; t < TC; ++t) {
        // ---- layer 1 (cur precomputed by GEMM, bias included) -------------
        int nib = 0;
        nib |= (int)lif_step(m1.x, cur.x, B1c.x, Th1v.x);
        nib |= (int)lif_step(m1.y, cur.y, B1c.y, Th1v.y) << 1;
        nib |= (int)lif_step(m1.z, cur.z, B1c.z, Th1v.z) << 2;
        nib |= (int)lif_step(m1.w, cur.w, B1c.w, Th1v.w) << 3;
        make_masks(nib, lane, M);
        int npad = compact(nib, lane, M, lst);
        if (t + 1 < TC) cur = *(const float4*)(curb + (size_t)(t + 1) * Hh);  // prefetch

        // ---- layer 2 ------------------------------------------------------
        float4 s = sum_h(lst, npad >> 3, Wt_h, offBh);
        nib  = (int)lif_step(m2.x, __fadd_rn(s.x, bhv.x), B2c.x, Th2v.x);
        nib |= (int)lif_step(m2.y, __fadd_rn(s.y, bhv.y), B2c.y, Th2v.y) << 1;
        nib |= (int)lif_step(m2.z, __fadd_rn(s.z, bhv.z), B2c.z, Th2v.z) << 2;
        nib |= (int)lif_step(m2.w, __fadd_rn(s.w, bhv.w), B2c.w, Th2v.w) << 3;
        make_masks(nib, lane, M);
        npad = compact(nib, lane, M, lst);

        // ---- layer 3 (reuses beta2/thr2 — source bug preserved) ----------
        s = sum_h(lst, npad >> 3, Wt_h1, offBh);
        nib  = (int)lif_step(m3.x, __fadd_rn(s.x, bh1v.x), B2c.x, Th2v.x);
        nib |= (int)lif_step(m3.y, __fadd_rn(s.y, bh1v.y), B2c.y, Th2v.y) << 1;
        nib |= (int)lif_step(m3.z, __fadd_rn(s.z, bh1v.z), B2c.z, Th2v.z) << 2;
        nib |= (int)lif_step(m3.w, __fadd_rn(s.w, bh1v.w), B2c.w, Th2v.w) << 3;
        make_masks(nib, lane, M);
        npad = compact(nib, lane, M, lst);

        // ---- output LI neurons (no reset), gather from LDS ---------------
        const float2 os = sum_o_lds(lst, npad >> 3, ldsO, offBo);
        mo0 = __fadd_rn(__fmul_rn(Bo0, mo0), __fadd_rn(os.x, bo0));
        mo1 = __fadd_rn(__fmul_rn(Bo1, mo1), __fadd_rn(os.y, bo1));
    }

    *(float4*)(m1s + (size_t)b * Hh + off4) = m1;
    *(float4*)(m2s + (size_t)b * Hh + off4) = m2;
    *(float4*)(m3s + (size_t)b * Hh + off4) = m3;
    *(float2*)(mos + (size_t)b * 128 + off2) = make_float2(mo0, mo1);

    float* dst = out + ((lane < 32) ? 0 : (size_t)Bsz * Oo) + (size_t)b * Oo + oo;
    const float o0 = (float)(1.0 / (1.0 + exp(-(double)mo0)));
    const float o1 = (float)(1.0 / (1.0 + exp(-(double)mo1)));
    *(float2*)dst = make_float2(o0, o1);
}

// ---------------- layer-1 GEMM, R12 form: 4h x 8t tile + w prefetch --------
// Block: 256 threads = 64 h-quads x 4 t-groups; TT=32 t-columns per block.
// Per d: 1 float4 w-load (1-deep prefetched) + broadcast LDS reads -> 32 fma.
// Bit-exact: per (h,t) c is a sequential fmaf chain over d ascending.
template<int TT>
__global__ __launch_bounds__(256) void gemm_l1_r8(
    const float* __restrict__ x, const float* __restrict__ Wt_in,
    const float* __restrict__ b_in, float* __restrict__ cur1,
    int tg_base, int TCloc)
{
    __shared__ float xs[Dd][TT];
    const int tid = threadIdx.x;
    const int b   = blockIdx.x;
    const int ty  = blockIdx.y;
    const int tg0 = tg_base + ty * TT;
    const float* xb = x + (size_t)b * Dd * Tt + tg0;
    constexpr int T4 = TT / 4;
    for (int v = tid; v < Dd * T4; v += 256) {
        const int d = v / T4, j4 = v - d * T4;
        *(float4*)&xs[d][j4 * 4] = *(const float4*)(xb + (size_t)d * Tt + j4 * 4);
    }
    __syncthreads();
    constexpr int TS = TT / 4;          // 8 t per thread
    const int hq = tid & 63;            // h base = 4*hq
    const int tq = tid >> 6;            // t base = TS*tq
    float c0[TS], c1[TS], c2[TS], c3[TS];
    #pragma unroll
    for (int j = 0; j < TS; ++j) { c0[j] = 0.f; c1[j] = 0.f; c2[j] = 0.f; c3[j] = 0.f; }
    const float* wp = Wt_in + hq * 4;
    float4 w = *(const float4*)(wp);
    #pragma unroll 4
    for (int d = 0; d < Dd; ++d) {
        float4 wn;
        if (d + 1 < Dd) wn = *(const float4*)(wp + (size_t)(d + 1) * Hh);  // prefetch
        #pragma unroll
        for (int j = 0; j < TS; ++j) {
            const float xv = xs[d][tq * TS + j];
            c0[j] = fmaf(w.x, xv, c0[j]);
            c1[j] = fmaf(w.y, xv, c1[j]);
            c2[j] = fmaf(w.z, xv, c2[j]);
            c3[j] = fmaf(w.w, xv, c3[j]);
        }
        w = wn;
    }
    const float4 bb = *(const float4*)(b_in + hq * 4);
    float* cb = cur1 + ((size_t)b * TCloc + ty * TT + tq * TS) * Hh + hq * 4;
    #pragma unroll
    for (int j = 0; j < TS; ++j) {
        float4 o;
        o.x = __fadd_rn(c0[j], bb.x);
        o.y = __fadd_rn(c1[j], bb.y);
        o.z = __fadd_rn(c2[j], bb.z);
        o.w = __fadd_rn(c3[j], bb.w);
        *(float4*)(cb + (size_t)j * Hh) = o;
    }
}

// ---- small-TC fallbacks (unchanged) ---------------------------------------
template<int TT>
__global__ __launch_bounds__(256) void gemm_l1_lds(
    const float* __restrict__ x, const float* __restrict__ Wt_in,
    const float* __restrict__ b_in, float* __restrict__ cur1,
    int tg_base, int TCloc)
{
    __shared__ float xs[Dd][TT];
    const int h   = threadIdx.x;
    const int b   = blockIdx.x;
    const int ty  = blockIdx.y;
    const int tg0 = tg_base + ty * TT;
    const float* xb = x + (size_t)b * Dd * Tt + tg0;
    constexpr int T4 = TT / 4;
    for (int v = threadIdx.x; v < Dd * T4; v += 256) {
        const int d = v / T4, j4 = v - d * T4;
        *(float4*)&xs[d][j4 * 4] = *(const float4*)(xb + (size_t)d * Tt + j4 * 4);
    }
    __syncthreads();
    float c[TT];
    #pragma unroll
    for (int j = 0; j < TT; ++j) c[j] = 0.f;
    for (int d = 0; d < Dd; ++d) {
        const float w = Wt_in[d * Hh + h];        // coalesced
        #pragma unroll
        for (int j = 0; j < TT; ++j) c[j] = fmaf(w, xs[d][j], c[j]);  // broadcast
    }
    const float bb = b_in[h];
    float* cb = cur1 + ((size_t)b * TCloc + ty * TT) * Hh;
    #pragma unroll
    for (int j = 0; j < TT; ++j) cb[j * Hh + h] = __fadd_rn(c[j], bb);
}

template<int TT>
__global__ __launch_bounds__(256) void gemm_l1_simple(
    const float* __restrict__ x, const float* __restrict__ Wt_in,
    const float* __restrict__ b_in, float* __restrict__ cur1, int tg0)
{
    const int h = threadIdx.x;
    const int b = blockIdx.x;
    float c[TT];
    #pragma unroll
    for (int j = 0; j < TT; ++j) c[j] = 0.f;
    const float* xb = x + (size_t)b * Dd * Tt + tg0;
    for (int d = 0; d < Dd; ++d) {
        const float w = Wt_in[d * Hh + h];
        const float* xp = xb + (size_t)d * Tt;
        #pragma unroll
        for (int j = 0; j < TT; ++j) c[j] = fmaf(w, xp[j], c[j]);
    }
    const float bb = b_in[h];
    float* cb = cur1 + (size_t)b * TT * Hh;
    #pragma unroll
    for (int j = 0; j < TT; ++j) cb[j * Hh + h] = __fadd_rn(c[j], bb);
}

} // namespace

extern "C" void kernel_launch(void* const* d_in, const int* in_sizes, int n_in,
                              void* d_out, int out_size, void* d_ws, size_t ws_size,
                              hipStream_t stream) {
    const float* x      = (const float*)d_in[0];
    const float* W_in   = (const float*)d_in[1];
    const float* b_in   = (const float*)d_in[2];
    const float* beta1  = (const float*)d_in[3];
    const float* thr1   = (const float*)d_in[4];
    const float* W_h    = (const float*)d_in[5];
    const float* b_h    = (const float*)d_in[6];
    const float* beta2  = (const float*)d_in[7];
    const float* thr2   = (const float*)d_in[8];
    const float* W_h1   = (const float*)d_in[9];
    const float* b_h1   = (const float*)d_in[10];
    const float* W_f    = (const float*)d_in[11];
    const float* b_f    = (const float*)d_in[12];
    const float* beta_f = (const float*)d_in[13];
    const float* W_a    = (const float*)d_in[14];
    const float* b_a    = (const float*)d_in[15];
    const float* beta_a = (const float*)d_in[16];
    float* out = (float*)d_out;

    float* ws = (float*)d_ws;
    size_t off = 0;
    auto alloc = [&](size_t n) { float* p = ws + off; off += n; return p; };
    float* Wt_in = alloc(257 * 256);
    float* Wt_h  = alloc(257 * 256);
    float* Wt_h1 = alloc(257 * 256);
    float* WtO   = alloc(257 * 128);
    float* m1s   = alloc((size_t)Bsz * Hh);
    float* m2s   = alloc((size_t)Bsz * Hh);
    float* m3s   = alloc((size_t)Bsz * Hh);
    float* mos   = alloc((size_t)Bsz * 128);
    const size_t fixed = off;

    int TC = 1;
    const int cands[8] = {128, 64, 32, 16, 8, 4, 2, 1};
    for (int i = 0; i < 8; ++i) {
        if ((fixed + (size_t)cands[i] * Bsz * Hh) * sizeof(float) <= ws_size) { TC = cands[i]; break; }
    }
    float* cur1 = alloc((size_t)TC * Bsz * Hh);

    pack_t<<<257, 256, 0, stream>>>(W_in, Wt_in, 256, 256);
    pack_t<<<257, 256, 0, stream>>>(W_h,  Wt_h,  256, 256);
    pack_t<<<257, 256, 0, stream>>>(W_h1, Wt_h1, 256, 256);
    pack_o<<<129, 256, 0, stream>>>(W_f, W_a, WtO);

    const int nch = Tt / TC;
    for (int c = 0; c < nch; ++c) {
        const int tg = c * TC;
        if (TC >= 32)
            gemm_l1_r8<32><<<dim3(Bsz, TC / 32), 256, 0, stream>>>(x, Wt_in, b_in, cur1, tg, TC);
        else if (TC == 16)
            gemm_l1_lds<16><<<dim3(Bsz, 1), 256, 0, stream>>>(x, Wt_in, b_in, cur1, tg, TC);
        else if (TC == 8)
            gemm_l1_lds<8><<<dim3(Bsz, 1), 256, 0, stream>>>(x, Wt_in, b_in, cur1, tg, TC);
        else if (TC == 4)
            gemm_l1_simple<4><<<Bsz, 256, 0, stream>>>(x, Wt_in, b_in, cur1, tg);
        else if (TC == 2)
            gemm_l1_simple<2><<<Bsz, 256, 0, stream>>>(x, Wt_in, b_in, cur1, tg);
        else
            gemm_l1_simple<1><<<Bsz, 256, 0, stream>>>(x, Wt_in, b_in, cur1, tg);

        snn_rec<<<Bsz / 4, 256, 0, stream>>>(
            cur1, Wt_h, Wt_h1, WtO,
            beta1, thr1, b_h, beta2, thr2, b_h1,
            b_f, beta_f, b_a, beta_a,
            m1s, m2s, m3s, mos, out, TC, (c == 0) ? 1 : 0);
    }
}